// Round 1
// baseline (548.464 us; speedup 1.0000x reference)
//
#include <hip/hip_runtime.h>
#include <hip/hip_bf16.h>
#include <math.h>

// Sizes fixed by the problem
#define BATCH 1024
#define FIN   256
#define HDIM  512
#define PDIM  128

#define TILE 16

// C[M,N] = A[M,K] @ W[N,K]^T + bias[N]
__global__ void gemm_bias(const float* __restrict__ A, const float* __restrict__ W,
                          const float* __restrict__ bias, float* __restrict__ C,
                          int M, int N, int K) {
    __shared__ float As[TILE][TILE + 1];
    __shared__ float Ws[TILE][TILE + 1];
    const int tx = threadIdx.x;   // n within tile
    const int ty = threadIdx.y;   // m within tile
    const int n = blockIdx.x * TILE + tx;
    const int m = blockIdx.y * TILE + ty;

    float acc = 0.0f;
    for (int kt = 0; kt < K; kt += TILE) {
        // cooperative loads (all dims are multiples of 16 -> no bounds checks)
        As[ty][tx] = A[m * K + kt + tx];
        Ws[ty][tx] = W[(blockIdx.x * TILE + ty) * K + kt + tx];
        __syncthreads();
#pragma unroll
        for (int kk = 0; kk < TILE; kk++) {
            acc = fmaf(As[ty][kk], Ws[tx][kk], acc);
        }
        __syncthreads();
    }
    C[m * N + n] = acc + bias[n];
}

// hout[b,i] = h[b,i] + sum_j softmax_j(q[b,i]*k[b,j]) * v[b,j]
// one block per batch element b
__global__ void attn_kernel(const float* __restrict__ h, const float* __restrict__ q,
                            const float* __restrict__ k, const float* __restrict__ v,
                            float* __restrict__ hout) {
    __shared__ float ks[HDIM];
    __shared__ float vs[HDIM];
    __shared__ float red[256];
    const int b = blockIdx.x;
    const int tid = threadIdx.x;

    for (int j = tid; j < HDIM; j += 256) {
        ks[j] = k[b * HDIM + j];
        vs[j] = v[b * HDIM + j];
    }
    __syncthreads();

    // kmax reduction
    float lmax = fmaxf(ks[tid], ks[tid + 256]);
    red[tid] = lmax;
    __syncthreads();
    for (int s = 128; s > 0; s >>= 1) {
        if (tid < s) red[tid] = fmaxf(red[tid], red[tid + s]);
        __syncthreads();
    }
    const float kmax = red[0];
    __syncthreads();

    // kmin reduction
    float lmin = fminf(ks[tid], ks[tid + 256]);
    red[tid] = lmin;
    __syncthreads();
    for (int s = 128; s > 0; s >>= 1) {
        if (tid < s) red[tid] = fminf(red[tid], red[tid + s]);
        __syncthreads();
    }
    const float kmin = red[0];

    for (int i = tid; i < HDIM; i += 256) {
        const float s = q[b * HDIM + i];
        const float m = (s > 0.0f) ? s * kmax : s * kmin;  // max_j s*k_j
        float D = 0.0f;
        float Nacc = 0.0f;
#pragma unroll 4
        for (int j = 0; j < HDIM; j++) {
            const float e = __expf(fmaf(s, ks[j], -m));
            D += e;
            Nacc = fmaf(e, vs[j], Nacc);
        }
        hout[b * HDIM + i] = h[b * HDIM + i] + Nacc / D;
    }
}

// hout = hin + gelu_exact(t)
__global__ void gelu_res(const float* __restrict__ hin, const float* __restrict__ t,
                         float* __restrict__ hout, int n) {
    const int i = blockIdx.x * 256 + threadIdx.x;
    if (i < n) {
        const float x = t[i];
        const float g = 0.5f * x * (1.0f + erff(x * 0.70710678118654752f));
        hout[i] = hin[i] + g;
    }
}

// out[b] = sum_p fea[b,p] * rw[p] + rb
__global__ void head_kernel(const float* __restrict__ fea, const float* __restrict__ rw,
                            const float* __restrict__ rb, float* __restrict__ out) {
    __shared__ float red[PDIM];
    const int b = blockIdx.x;
    const int tid = threadIdx.x;
    red[tid] = fea[b * PDIM + tid] * rw[tid];
    __syncthreads();
    for (int s = 64; s > 0; s >>= 1) {
        if (tid < s) red[tid] += red[tid + s];
        __syncthreads();
    }
    if (tid == 0) out[b] = red[0] + rb[0];
}

extern "C" void kernel_launch(void* const* d_in, const int* in_sizes, int n_in,
                              void* d_out, int out_size, void* d_ws, size_t ws_size,
                              hipStream_t stream) {
    // inputs (setup_inputs dict order)
    const float* x      = (const float*)d_in[0];
    const float* lin0_w = (const float*)d_in[1];
    const float* lin0_b = (const float*)d_in[2];
    const float* b1_qw  = (const float*)d_in[3];
    const float* b1_qb  = (const float*)d_in[4];
    const float* b1_kw  = (const float*)d_in[5];
    const float* b1_kb  = (const float*)d_in[6];
    const float* b1_vw  = (const float*)d_in[7];
    const float* b1_vb  = (const float*)d_in[8];
    const float* b1_f1w = (const float*)d_in[9];
    const float* b1_f1b = (const float*)d_in[10];
    const float* b2_qw  = (const float*)d_in[11];
    const float* b2_qb  = (const float*)d_in[12];
    const float* b2_kw  = (const float*)d_in[13];
    const float* b2_kb  = (const float*)d_in[14];
    const float* b2_vw  = (const float*)d_in[15];
    const float* b2_vb  = (const float*)d_in[16];
    const float* b2_f1w = (const float*)d_in[17];
    const float* b2_f1b = (const float*)d_in[18];
    const float* fea_w  = (const float*)d_in[19];
    const float* fea_b  = (const float*)d_in[20];
    const float* reg_w  = (const float*)d_in[21];
    const float* reg_b  = (const float*)d_in[22];

    float* out = (float*)d_out;          // [1024]
    float* fea = out + BATCH;            // [1024,128] directly in d_out

    // workspace: 6 buffers of BATCH*HDIM floats (12 MB total)
    const size_t BUF = (size_t)BATCH * HDIM;
    float* ws = (float*)d_ws;
    float* hA  = ws + 0 * BUF;
    float* hB  = ws + 1 * BUF;
    float* qb_ = ws + 2 * BUF;
    float* kb_ = ws + 3 * BUF;
    float* vb_ = ws + 4 * BUF;
    float* tmp = ws + 5 * BUF;

    const dim3 blk(TILE, TILE);
    const dim3 grid_h(HDIM / TILE, BATCH / TILE);   // N=512
    const dim3 grid_p(PDIM / TILE, BATCH / TILE);   // N=128
    const int NEPB = (int)BUF;                      // elementwise count

    // lin0: hA = x @ lin0_w^T + b
    gemm_bias<<<grid_h, blk, 0, stream>>>(x, lin0_w, lin0_b, hA, BATCH, HDIM, FIN);

    // ---- block 1 ----
    gemm_bias<<<grid_h, blk, 0, stream>>>(hA, b1_qw, b1_qb, qb_, BATCH, HDIM, HDIM);
    gemm_bias<<<grid_h, blk, 0, stream>>>(hA, b1_kw, b1_kb, kb_, BATCH, HDIM, HDIM);
    gemm_bias<<<grid_h, blk, 0, stream>>>(hA, b1_vw, b1_vb, vb_, BATCH, HDIM, HDIM);
    attn_kernel<<<BATCH, 256, 0, stream>>>(hA, qb_, kb_, vb_, hB);
    gemm_bias<<<grid_h, blk, 0, stream>>>(hB, b1_f1w, b1_f1b, tmp, BATCH, HDIM, HDIM);
    gelu_res<<<(NEPB + 255) / 256, 256, 0, stream>>>(hB, tmp, hA, NEPB);

    // ---- block 2 ----
    gemm_bias<<<grid_h, blk, 0, stream>>>(hA, b2_qw, b2_qb, qb_, BATCH, HDIM, HDIM);
    gemm_bias<<<grid_h, blk, 0, stream>>>(hA, b2_kw, b2_kb, kb_, BATCH, HDIM, HDIM);
    gemm_bias<<<grid_h, blk, 0, stream>>>(hA, b2_vw, b2_vb, vb_, BATCH, HDIM, HDIM);
    attn_kernel<<<BATCH, 256, 0, stream>>>(hA, qb_, kb_, vb_, hB);
    gemm_bias<<<grid_h, blk, 0, stream>>>(hB, b2_f1w, b2_f1b, tmp, BATCH, HDIM, HDIM);
    gelu_res<<<(NEPB + 255) / 256, 256, 0, stream>>>(hB, tmp, hA, NEPB);

    // ---- heads ----
    gemm_bias<<<grid_p, blk, 0, stream>>>(hA, fea_w, fea_b, fea, BATCH, PDIM, HDIM);
    head_kernel<<<BATCH, PDIM, 0, stream>>>(fea, reg_w, reg_b, out);
}

// Round 2
// 267.081 us; speedup vs baseline: 2.0535x; 2.0535x over previous
//
#include <hip/hip_runtime.h>
#include <math.h>

#define BATCH 1024
#define FIN   256
#define HDIM  512
#define PDIM  128

typedef unsigned short u16;
typedef __attribute__((ext_vector_type(8))) short short8;
typedef __attribute__((ext_vector_type(4))) float fx4;

__device__ __forceinline__ float b2f(u16 b) {
    return __uint_as_float(((unsigned)b) << 16);
}
__device__ __forceinline__ u16 f2b(float f) {
    unsigned u = __float_as_uint(f);
    u += 0x7fffu + ((u >> 16) & 1u);   // RNE
    return (u16)(u >> 16);
}

// ---------------- fp32 -> bf16 conversion (x + 11 weight matrices) ----------
#define NCVT 11
struct CvtArgs {
    const float* src[NCVT];
    u16* dst[NCVT];
    int n[NCVT];
};

__global__ __launch_bounds__(256) void cvt_kernel(CvtArgs a) {
    const int t = blockIdx.y;
    const int i = (blockIdx.x * 256 + threadIdx.x) * 4;
    if (i >= a.n[t]) return;
    const float4 f = *(const float4*)(a.src[t] + i);
    ushort4 o;
    o.x = f2b(f.x); o.y = f2b(f.y); o.z = f2b(f.z); o.w = f2b(f.w);
    *(ushort4*)(a.dst[t] + i) = o;
}

// ---------------- bf16 MFMA GEMM:  C[M,Nper] = A[M,K] @ W[Nper,K]^T + bias --
// EPI 0: store bf16(acc+bias)
// EPI 1: store bf16(res + gelu(acc+bias))
// EPI 2: store fp32(acc+bias)
// Up to 3 weight/out sets (fused qkv) selected by blockIdx.x / tilesPerW.
#define BM 64
#define BN 64
#define BK 64
#define LDK 72   // +8 bf16 pad: row stride 144B -> fragment b128 reads are <=2-way (free)

template<int EPI>
__global__ __launch_bounds__(256) void gemm_k(
    const u16* __restrict__ A,
    const u16* __restrict__ W0, const u16* __restrict__ W1, const u16* __restrict__ W2,
    const float* __restrict__ bi0, const float* __restrict__ bi1, const float* __restrict__ bi2,
    u16* __restrict__ o0, u16* __restrict__ o1, u16* __restrict__ o2,
    float* __restrict__ of, const u16* __restrict__ res,
    int Nper, int K, int tilesPerW)
{
    __shared__ __align__(16) u16 As[BM * LDK];
    __shared__ __align__(16) u16 Ws[BM * LDK];

    const int tid  = threadIdx.x;
    const int lane = tid & 63;
    const int wave = tid >> 6;
    const int wm = wave & 1, wn = wave >> 1;     // 2x2 waves over 64x64 tile
    const int quad = lane >> 4, l16 = lane & 15;

    const int which = blockIdx.x / tilesPerW;
    const int bn = (blockIdx.x % tilesPerW) * BN;
    const int bm = blockIdx.y * BM;

    const u16* W   = (which == 0) ? W0  : (which == 1) ? W1  : W2;
    const float* bi = (which == 0) ? bi0 : (which == 1) ? bi1 : bi2;
    u16* ob        = (which == 0) ? o0  : (which == 1) ? o1  : o2;

    const int srow = tid >> 3;          // 0..31
    const int scol = (tid & 7) * 8;     // 0,8,...,56

    fx4 acc[2][2] = {};

    for (int kt = 0; kt < K; kt += BK) {
#pragma unroll
        for (int c = 0; c < 2; c++) {
            const int r = srow + 32 * c;
            *(short8*)&As[r * LDK + scol] =
                *(const short8*)&A[(size_t)(bm + r) * K + kt + scol];
            *(short8*)&Ws[r * LDK + scol] =
                *(const short8*)&W[(size_t)(bn + r) * K + kt + scol];
        }
        __syncthreads();
#pragma unroll
        for (int k0 = 0; k0 < BK; k0 += 32) {
            const short8 a0 = *(const short8*)&As[(wm * 32 +      l16) * LDK + k0 + quad * 8];
            const short8 a1 = *(const short8*)&As[(wm * 32 + 16 + l16) * LDK + k0 + quad * 8];
            const short8 b0 = *(const short8*)&Ws[(wn * 32 +      l16) * LDK + k0 + quad * 8];
            const short8 b1 = *(const short8*)&Ws[(wn * 32 + 16 + l16) * LDK + k0 + quad * 8];
            acc[0][0] = __builtin_amdgcn_mfma_f32_16x16x32_bf16(a0, b0, acc[0][0], 0, 0, 0);
            acc[0][1] = __builtin_amdgcn_mfma_f32_16x16x32_bf16(a0, b1, acc[0][1], 0, 0, 0);
            acc[1][0] = __builtin_amdgcn_mfma_f32_16x16x32_bf16(a1, b0, acc[1][0], 0, 0, 0);
            acc[1][1] = __builtin_amdgcn_mfma_f32_16x16x32_bf16(a1, b1, acc[1][1], 0, 0, 0);
        }
        __syncthreads();
    }

#pragma unroll
    for (int i = 0; i < 2; i++) {
#pragma unroll
        for (int j = 0; j < 2; j++) {
            const int n_ = bn + wn * 32 + j * 16 + l16;
            const float bv = bi[n_];
#pragma unroll
            for (int r = 0; r < 4; r++) {
                const int m_ = bm + wm * 32 + i * 16 + quad * 4 + r;
                const float vacc = acc[i][j][r] + bv;
                const size_t idx = (size_t)m_ * Nper + n_;
                if (EPI == 0) {
                    ob[idx] = f2b(vacc);
                } else if (EPI == 1) {
                    const float g = 0.5f * vacc * (1.0f + erff(vacc * 0.70710678118654752f));
                    ob[idx] = f2b(b2f(res[idx]) + g);
                } else {
                    of[idx] = vacc;
                }
            }
        }
    }
}

// ---------------- attention: hout = h + softmax_j(q_i*k_j) @ v --------------
__global__ __launch_bounds__(256) void attn_kernel(
    const u16* __restrict__ h, const u16* __restrict__ q,
    const u16* __restrict__ k, const u16* __restrict__ v,
    u16* __restrict__ hout)
{
    __shared__ __align__(16) float ks[HDIM];
    __shared__ __align__(16) float vs[HDIM];
    __shared__ float rmax[4], rmin[4];

    const int b = blockIdx.x;
    const int tid = threadIdx.x;
    const int i0 = tid, i1 = tid + 256;
    const size_t base = (size_t)b * HDIM;

    const float k0 = b2f(k[base + i0]);
    const float k1 = b2f(k[base + i1]);
    ks[i0] = k0; ks[i1] = k1;
    vs[i0] = b2f(v[base + i0]);
    vs[i1] = b2f(v[base + i1]);

    float lmax = fmaxf(k0, k1), lmin = fminf(k0, k1);
#pragma unroll
    for (int off = 32; off; off >>= 1) {
        lmax = fmaxf(lmax, __shfl_xor(lmax, off));
        lmin = fminf(lmin, __shfl_xor(lmin, off));
    }
    if ((tid & 63) == 0) { rmax[tid >> 6] = lmax; rmin[tid >> 6] = lmin; }
    __syncthreads();
    const float kmax = fmaxf(fmaxf(rmax[0], rmax[1]), fmaxf(rmax[2], rmax[3]));
    const float kmin = fminf(fminf(rmin[0], rmin[1]), fminf(rmin[2], rmin[3]));

    const float s0 = b2f(q[base + i0]);
    const float s1 = b2f(q[base + i1]);
    const float m0 = (s0 > 0.0f) ? s0 * kmax : s0 * kmin;
    const float m1 = (s1 > 0.0f) ? s1 * kmax : s1 * kmin;

    float D0 = 0.f, N0 = 0.f, D1 = 0.f, N1 = 0.f;
    const float4* k4 = (const float4*)ks;
    const float4* v4 = (const float4*)vs;
#pragma unroll 4
    for (int j = 0; j < HDIM / 4; j++) {
        const float4 kk = k4[j];
        const float4 vv = v4[j];
        float e;
        e = __expf(fmaf(s0, kk.x, -m0)); D0 += e; N0 = fmaf(e, vv.x, N0);
        e = __expf(fmaf(s0, kk.y, -m0)); D0 += e; N0 = fmaf(e, vv.y, N0);
        e = __expf(fmaf(s0, kk.z, -m0)); D0 += e; N0 = fmaf(e, vv.z, N0);
        e = __expf(fmaf(s0, kk.w, -m0)); D0 += e; N0 = fmaf(e, vv.w, N0);
        e = __expf(fmaf(s1, kk.x, -m1)); D1 += e; N1 = fmaf(e, vv.x, N1);
        e = __expf(fmaf(s1, kk.y, -m1)); D1 += e; N1 = fmaf(e, vv.y, N1);
        e = __expf(fmaf(s1, kk.z, -m1)); D1 += e; N1 = fmaf(e, vv.z, N1);
        e = __expf(fmaf(s1, kk.w, -m1)); D1 += e; N1 = fmaf(e, vv.w, N1);
    }
    hout[base + i0] = f2b(b2f(h[base + i0]) + N0 / D0);
    hout[base + i1] = f2b(b2f(h[base + i1]) + N1 / D1);
}

// ---------------- regression head: out[b] = fea[b,:] . rw + rb --------------
__global__ __launch_bounds__(128) void head_kernel(
    const float* __restrict__ fea, const float* __restrict__ rw,
    const float* __restrict__ rb, float* __restrict__ out)
{
    __shared__ float red[PDIM];
    const int b = blockIdx.x;
    const int tid = threadIdx.x;
    red[tid] = fea[b * PDIM + tid] * rw[tid];
    __syncthreads();
    for (int s = 64; s > 0; s >>= 1) {
        if (tid < s) red[tid] += red[tid + s];
        __syncthreads();
    }
    if (tid == 0) out[b] = red[0] + rb[0];
}

extern "C" void kernel_launch(void* const* d_in, const int* in_sizes, int n_in,
                              void* d_out, int out_size, void* d_ws, size_t ws_size,
                              hipStream_t stream) {
    const float* x      = (const float*)d_in[0];
    const float* lin0_w = (const float*)d_in[1];
    const float* lin0_b = (const float*)d_in[2];
    const float* b1_qw  = (const float*)d_in[3];
    const float* b1_qb  = (const float*)d_in[4];
    const float* b1_kw  = (const float*)d_in[5];
    const float* b1_kb  = (const float*)d_in[6];
    const float* b1_vw  = (const float*)d_in[7];
    const float* b1_vb  = (const float*)d_in[8];
    const float* b1_f1w = (const float*)d_in[9];
    const float* b1_f1b = (const float*)d_in[10];
    const float* b2_qw  = (const float*)d_in[11];
    const float* b2_qb  = (const float*)d_in[12];
    const float* b2_kw  = (const float*)d_in[13];
    const float* b2_kb  = (const float*)d_in[14];
    const float* b2_vw  = (const float*)d_in[15];
    const float* b2_vb  = (const float*)d_in[16];
    const float* b2_f1w = (const float*)d_in[17];
    const float* b2_f1b = (const float*)d_in[18];
    const float* fea_w  = (const float*)d_in[19];
    const float* fea_b  = (const float*)d_in[20];
    const float* reg_w  = (const float*)d_in[21];
    const float* reg_b  = (const float*)d_in[22];

    float* out = (float*)d_out;        // [1024]
    float* fea = out + BATCH;          // [1024,128] fp32 directly in d_out

    // ---- workspace layout (bf16 elements) ----
    u16* wsb = (u16*)d_ws;
    const size_t SZ_X  = (size_t)BATCH * FIN;     // 262144
    const size_t SZ_L0 = (size_t)HDIM * FIN;      // 131072
    const size_t SZ_HH = (size_t)HDIM * HDIM;     // 262144
    const size_t SZ_FE = (size_t)PDIM * HDIM;     // 65536
    const size_t SZ_AC = (size_t)BATCH * HDIM;    // 524288

    u16* xb   = wsb;
    u16* wl0  = xb + SZ_X;
    u16* w1q  = wl0 + SZ_L0;
    u16* w1k  = w1q + SZ_HH;
    u16* w1v  = w1k + SZ_HH;
    u16* w1f  = w1v + SZ_HH;
    u16* w2q  = w1f + SZ_HH;
    u16* w2k  = w2q + SZ_HH;
    u16* w2v  = w2k + SZ_HH;
    u16* w2f  = w2v + SZ_HH;
    u16* wfe  = w2f + SZ_HH;
    u16* hA   = wfe + SZ_FE;
    u16* hB   = hA + SZ_AC;
    u16* qb   = hB + SZ_AC;
    u16* kb   = qb + SZ_AC;
    u16* vb   = kb + SZ_AC;

    // ---- conversion ----
    CvtArgs ca;
    const float* srcs[NCVT] = {x, lin0_w, b1_qw, b1_kw, b1_vw, b1_f1w,
                               b2_qw, b2_kw, b2_vw, b2_f1w, fea_w};
    u16* dsts[NCVT] = {xb, wl0, w1q, w1k, w1v, w1f, w2q, w2k, w2v, w2f, wfe};
    const int ns[NCVT] = {(int)SZ_X, (int)SZ_L0, (int)SZ_HH, (int)SZ_HH, (int)SZ_HH,
                          (int)SZ_HH, (int)SZ_HH, (int)SZ_HH, (int)SZ_HH, (int)SZ_HH,
                          (int)SZ_FE};
    for (int i = 0; i < NCVT; i++) { ca.src[i] = srcs[i]; ca.dst[i] = dsts[i]; ca.n[i] = ns[i]; }
    cvt_kernel<<<dim3(256, NCVT), 256, 0, stream>>>(ca);

    const dim3 blk(256);
    const dim3 g_lin0(HDIM / BN, BATCH / BM);        // (8,16)
    const dim3 g_qkv(3 * HDIM / BN, BATCH / BM);     // (24,16)
    const dim3 g_fc1(HDIM / BN, BATCH / BM);         // (8,16)
    const dim3 g_fea(PDIM / BN, BATCH / BM);         // (2,16)

    // lin0: hA = bf16(x @ lin0_w^T + b)
    gemm_k<0><<<g_lin0, blk, 0, stream>>>(xb, wl0, wl0, wl0, lin0_b, lin0_b, lin0_b,
                                          hA, hA, hA, nullptr, nullptr,
                                          HDIM, FIN, HDIM / BN);

    // ---- block 1 ----
    gemm_k<0><<<g_qkv, blk, 0, stream>>>(hA, w1q, w1k, w1v, b1_qb, b1_kb, b1_vb,
                                         qb, kb, vb, nullptr, nullptr,
                                         HDIM, HDIM, HDIM / BN);
    attn_kernel<<<BATCH, blk, 0, stream>>>(hA, qb, kb, vb, hB);
    gemm_k<1><<<g_fc1, blk, 0, stream>>>(hB, w1f, w1f, w1f, b1_f1b, b1_f1b, b1_f1b,
                                         hA, hA, hA, nullptr, hB,
                                         HDIM, HDIM, HDIM / BN);

    // ---- block 2 ----
    gemm_k<0><<<g_qkv, blk, 0, stream>>>(hA, w2q, w2k, w2v, b2_qb, b2_kb, b2_vb,
                                         qb, kb, vb, nullptr, nullptr,
                                         HDIM, HDIM, HDIM / BN);
    attn_kernel<<<BATCH, blk, 0, stream>>>(hA, qb, kb, vb, hB);
    gemm_k<1><<<g_fc1, blk, 0, stream>>>(hB, w2f, w2f, w2f, b2_f1b, b2_f1b, b2_f1b,
                                         hA, hA, hA, nullptr, hB,
                                         HDIM, HDIM, HDIM / BN);

    // ---- heads ----
    gemm_k<2><<<g_fea, blk, 0, stream>>>(hA, wfe, wfe, wfe, fea_b, fea_b, fea_b,
                                         nullptr, nullptr, nullptr, fea, nullptr,
                                         PDIM, HDIM, PDIM / BN);
    head_kernel<<<BATCH, 128, 0, stream>>>(fea, reg_w, reg_b, out);
}